// Round 9
// baseline (34.900 us; speedup 1.0000x reference)
//
#include <hip/hip_runtime.h>
#include <math.h>

#define TOKEN_NUMS 2004
#define PAD_IDX    2003
#define B_DIM      32
#define S_DIM      512
#define SP_DIM     510              // S - 2
#define NROWS      (B_DIM * SP_DIM) // 16320
#define NCHUNKS    (NROWS / 64)     // 255
#define ROW_F4     (TOKEN_NUMS / 4) // 501 float4s per row

typedef float f32x4 __attribute__((ext_vector_type(4)));

// ---------------- Kernel 1: per-row argmax, 1 row/wave, PLAIN loads ----------------
// R8 structure minus nt: graph replays re-read pred, so let L2/L3 retain it
// (R5/R6 replay counters showed ~half of pred L3-resident without nt).
__global__ __launch_bounds__(1024) void cvl_argmax_kernel(
    const float* __restrict__ pred, int* __restrict__ tok)
{
    int wid  = (int)((blockIdx.x * blockDim.x + threadIdx.x) >> 6); // 0..16319
    int lane = (int)(threadIdx.x & 63);

    int b = wid / SP_DIM;
    int s = wid - b * SP_DIM;
    const f32x4* row = reinterpret_cast<const f32x4*>(
        pred + (size_t)(b * S_DIM + s) * TOKEN_NUMS);

    f32x4 v[8];
    #pragma unroll
    for (int k = 0; k < 7; ++k) v[k] = row[lane + 64 * k];
    int j7 = lane + 448; if (j7 > ROW_F4 - 1) j7 = ROW_F4 - 1;  // clamp -> full-wave op
    v[7] = row[j7];
    if (lane >= ROW_F4 - 448)                                    // mask duplicate reads
        v[7] = (f32x4){-INFINITY, -INFINITY, -INFINITY, -INFINITY};

    float best = -INFINITY;
    int   bidx = 0x7fffffff;
    #pragma unroll
    for (int k = 0; k < 7; ++k) {
        int base = (lane + 64 * k) << 2;
        if (v[k].x > best) { best = v[k].x; bidx = base;     }
        if (v[k].y > best) { best = v[k].y; bidx = base + 1; }
        if (v[k].z > best) { best = v[k].z; bidx = base + 2; }
        if (v[k].w > best) { best = v[k].w; bidx = base + 3; }
    }
    {
        int base = j7 << 2;
        if (v[7].x > best) { best = v[7].x; bidx = base;     }
        if (v[7].y > best) { best = v[7].y; bidx = base + 1; }
        if (v[7].z > best) { best = v[7].z; bidx = base + 2; }
        if (v[7].w > best) { best = v[7].w; bidx = base + 3; }
    }
    #pragma unroll
    for (int off = 32; off >= 1; off >>= 1) {
        float ov = __shfl_xor(best, off);
        int   oi = __shfl_xor(bidx, off);
        if (ov > best || (ov == best && oi < bidx)) { best = ov; bidx = oi; }
    }
    if (lane == 0) tok[wid] = bidx;
}

// ---------------- Kernel 2: R4's proven loss kernel (verbatim) ----------------
__global__ __launch_bounds__(1024) void cvl_loss_kernel(
    const int*   __restrict__ tok,
    const float* __restrict__ gt_acc,
    const float* __restrict__ gt_steer,
    const int*   __restrict__ gt_rev,
    float*       __restrict__ out)
{
    __shared__ int   s_cnt[256];
    __shared__ int   s_base[256];
    __shared__ float s_red[3][16];

    int tid  = (int)threadIdx.x;
    int wv   = tid >> 6;
    int lane = tid & 63;

    if (tid == 0) s_cnt[255] = 0;

    int tk[16];
    #pragma unroll
    for (int k = 0; k < 16; ++k) {
        int c = wv * 16 + k;
        tk[k] = (c < NCHUNKS) ? tok[c * 64 + lane] : PAD_IDX;
    }
    #pragma unroll
    for (int k = 0; k < 16; ++k) {
        int c = wv * 16 + k;
        if (c < NCHUNKS) {
            unsigned long long m = __ballot(tk[k] != PAD_IDX);
            if (lane == 0) s_cnt[c] = __popcll(m);
        }
    }
    __syncthreads();

    if (wv == 0) {
        int c0 = lane << 2;
        int a0 = s_cnt[c0], a1 = s_cnt[c0 + 1], a2 = s_cnt[c0 + 2], a3 = s_cnt[c0 + 3];
        int ls = a0 + a1 + a2 + a3;
        int incl = ls;
        #pragma unroll
        for (int off = 1; off <= 32; off <<= 1) {
            int u = __shfl_up(incl, off);
            if (lane >= off) incl += u;
        }
        int base = incl - ls;
        s_base[c0]     = base;
        s_base[c0 + 1] = base + a0;
        s_base[c0 + 2] = base + a0 + a1;
        s_base[c0 + 3] = base + a0 + a1 + a2;
    }
    __syncthreads();

    int   total = s_base[255];
    float cnt   = fmaxf((float)total, 1.0f);
    const float lse   = log1pf(expf(1.0f));
    const float scale = 1.0f / 9.0f;

    int pos[16];
    #pragma unroll
    for (int k = 0; k < 16; ++k) {
        int c = wv * 16 + k;
        if (c < NCHUNKS) {
            unsigned long long m = __ballot(tk[k] != PAD_IDX);
            int p = s_base[c] + __popcll(m & ((1ull << lane) - 1ull));
            pos[k] = (p < NROWS) ? p : 0;
        } else {
            pos[k] = 0;
        }
    }

    float accAS = 0.0f, accR = 0.0f, ceC = 0.0f;
    #pragma unroll
    for (int k = 0; k < 16; ++k) {
        int c = wv * 16 + k;
        bool valid = (c < NCHUNKS) && (tk[k] != PAD_IDX);
        float ga = gt_acc[pos[k]];
        float gs = gt_steer[pos[k]];
        int   gr = gt_rev[pos[k]];
        if (valid) {
            int t2  = tk[k];
            int rev = t2 & 1;
            int st  = (t2 >> 1) % 10;
            int bt  = (t2 / 20) % 10;
            int tt  = (t2 / 200) % 10;

            float acc_p   = (float)tt * scale - (float)bt * scale;
            float steer_p = (float)st * scale * 2.0f - 1.0f;

            float d = acc_p - ga;
            float a = fabsf(d);
            accAS += (a < 1.0f) ? 0.5f * d * d : a - 0.5f;

            d = steer_p - gs;
            a = fabsf(d);
            accAS += (a < 1.0f) ? 0.5f * d * d : a - 0.5f;

            if (gr != PAD_IDX) {
                accR += lse - ((rev == gr) ? 1.0f : 0.0f);
                ceC  += 1.0f;
            }
        }
    }

    #pragma unroll
    for (int o = 32; o >= 1; o >>= 1) {
        accAS += __shfl_down(accAS, o);
        accR  += __shfl_down(accR,  o);
        ceC   += __shfl_down(ceC,   o);
    }
    if (lane == 0) { s_red[0][wv] = accAS; s_red[1][wv] = accR; s_red[2][wv] = ceC; }
    __syncthreads();

    if (tid == 0) {
        float rAS = 0.0f, rR = 0.0f, rC = 0.0f;
        #pragma unroll
        for (int w = 0; w < 16; ++w) {
            rAS += s_red[0][w]; rR += s_red[1][w]; rC += s_red[2][w];
        }
        out[0] = rAS / cnt;
        out[1] = rR / fmaxf(rC, 1.0f);
    }
}

extern "C" void kernel_launch(void* const* d_in, const int* in_sizes, int n_in,
                              void* d_out, int out_size, void* d_ws, size_t ws_size,
                              hipStream_t stream)
{
    const float* pred     = (const float*)d_in[0];
    const float* gt_acc   = (const float*)d_in[1];
    const float* gt_steer = (const float*)d_in[2];
    const int*   gt_rev   = (const int*)d_in[3];
    float*       out      = (float*)d_out;
    int*         tok      = (int*)d_ws;   // NROWS ints = 65280 B

    int blocks = NROWS / 16;              // 1020 blocks, 16 waves/block, 1 row/wave
    hipLaunchKernelGGL(cvl_argmax_kernel, dim3(blocks), dim3(1024), 0, stream, pred, tok);
    hipLaunchKernelGGL(cvl_loss_kernel, dim3(1), dim3(1024), 0, stream,
                       tok, gt_acc, gt_steer, gt_rev, out);
}

// Round 10
// 32.495 us; speedup vs baseline: 1.0740x; 1.0740x over previous
//
#include <hip/hip_runtime.h>
#include <math.h>

#define TOKEN_NUMS 2004
#define PAD_IDX    2003
#define B_DIM      32
#define S_DIM      512
#define SP_DIM     510              // S - 2
#define NROWS      (B_DIM * SP_DIM) // 16320
#define NCHUNKS    (NROWS / 64)     // 255
#define ROW_F4     (TOKEN_NUMS / 4) // 501 float4s per row

typedef float f32x4 __attribute__((ext_vector_type(4)));

// ---------------- Kernel 1: per-row argmax, 1 row/wave, nt loads ----------------
// R8 configuration (proven best, 32.5 us): nontemporal loads (R9 A/B showed +2.4 us
// without them), full-64-lane clamped tail load, 1020x1024 grid.
__global__ __launch_bounds__(1024) void cvl_argmax_kernel(
    const float* __restrict__ pred, int* __restrict__ tok)
{
    int wid  = (int)((blockIdx.x * blockDim.x + threadIdx.x) >> 6); // 0..16319
    int lane = (int)(threadIdx.x & 63);

    int b = wid / SP_DIM;
    int s = wid - b * SP_DIM;
    const f32x4* row = reinterpret_cast<const f32x4*>(
        pred + (size_t)(b * S_DIM + s) * TOKEN_NUMS);

    f32x4 v[8];
    #pragma unroll
    for (int k = 0; k < 7; ++k)
        v[k] = __builtin_nontemporal_load(&row[lane + 64 * k]);
    int j7 = lane + 448; if (j7 > ROW_F4 - 1) j7 = ROW_F4 - 1;  // clamp -> full-wave op
    v[7] = __builtin_nontemporal_load(&row[j7]);
    if (lane >= ROW_F4 - 448)                                    // mask duplicate reads
        v[7] = (f32x4){-INFINITY, -INFINITY, -INFINITY, -INFINITY};

    float best = -INFINITY;
    int   bidx = 0x7fffffff;
    #pragma unroll
    for (int k = 0; k < 7; ++k) {
        int base = (lane + 64 * k) << 2;
        if (v[k].x > best) { best = v[k].x; bidx = base;     }
        if (v[k].y > best) { best = v[k].y; bidx = base + 1; }
        if (v[k].z > best) { best = v[k].z; bidx = base + 2; }
        if (v[k].w > best) { best = v[k].w; bidx = base + 3; }
    }
    {
        int base = j7 << 2;
        if (v[7].x > best) { best = v[7].x; bidx = base;     }
        if (v[7].y > best) { best = v[7].y; bidx = base + 1; }
        if (v[7].z > best) { best = v[7].z; bidx = base + 2; }
        if (v[7].w > best) { best = v[7].w; bidx = base + 3; }
    }
    #pragma unroll
    for (int off = 32; off >= 1; off >>= 1) {
        float ov = __shfl_xor(best, off);
        int   oi = __shfl_xor(bidx, off);
        if (ov > best || (ov == best && oi < bidx)) { best = ov; bidx = oi; }
    }
    if (lane == 0) tok[wid] = bidx;
}

// ---------------- Kernel 2: R4's proven loss kernel (verbatim) ----------------
__global__ __launch_bounds__(1024) void cvl_loss_kernel(
    const int*   __restrict__ tok,
    const float* __restrict__ gt_acc,
    const float* __restrict__ gt_steer,
    const int*   __restrict__ gt_rev,
    float*       __restrict__ out)
{
    __shared__ int   s_cnt[256];
    __shared__ int   s_base[256];
    __shared__ float s_red[3][16];

    int tid  = (int)threadIdx.x;
    int wv   = tid >> 6;
    int lane = tid & 63;

    if (tid == 0) s_cnt[255] = 0;

    int tk[16];
    #pragma unroll
    for (int k = 0; k < 16; ++k) {
        int c = wv * 16 + k;
        tk[k] = (c < NCHUNKS) ? tok[c * 64 + lane] : PAD_IDX;
    }
    #pragma unroll
    for (int k = 0; k < 16; ++k) {
        int c = wv * 16 + k;
        if (c < NCHUNKS) {
            unsigned long long m = __ballot(tk[k] != PAD_IDX);
            if (lane == 0) s_cnt[c] = __popcll(m);
        }
    }
    __syncthreads();

    if (wv == 0) {
        int c0 = lane << 2;
        int a0 = s_cnt[c0], a1 = s_cnt[c0 + 1], a2 = s_cnt[c0 + 2], a3 = s_cnt[c0 + 3];
        int ls = a0 + a1 + a2 + a3;
        int incl = ls;
        #pragma unroll
        for (int off = 1; off <= 32; off <<= 1) {
            int u = __shfl_up(incl, off);
            if (lane >= off) incl += u;
        }
        int base = incl - ls;
        s_base[c0]     = base;
        s_base[c0 + 1] = base + a0;
        s_base[c0 + 2] = base + a0 + a1;
        s_base[c0 + 3] = base + a0 + a1 + a2;
    }
    __syncthreads();

    int   total = s_base[255];
    float cnt   = fmaxf((float)total, 1.0f);
    const float lse   = log1pf(expf(1.0f));
    const float scale = 1.0f / 9.0f;

    int pos[16];
    #pragma unroll
    for (int k = 0; k < 16; ++k) {
        int c = wv * 16 + k;
        if (c < NCHUNKS) {
            unsigned long long m = __ballot(tk[k] != PAD_IDX);
            int p = s_base[c] + __popcll(m & ((1ull << lane) - 1ull));
            pos[k] = (p < NROWS) ? p : 0;
        } else {
            pos[k] = 0;
        }
    }

    float accAS = 0.0f, accR = 0.0f, ceC = 0.0f;
    #pragma unroll
    for (int k = 0; k < 16; ++k) {
        int c = wv * 16 + k;
        bool valid = (c < NCHUNKS) && (tk[k] != PAD_IDX);
        float ga = gt_acc[pos[k]];
        float gs = gt_steer[pos[k]];
        int   gr = gt_rev[pos[k]];
        if (valid) {
            int t2  = tk[k];
            int rev = t2 & 1;
            int st  = (t2 >> 1) % 10;
            int bt  = (t2 / 20) % 10;
            int tt  = (t2 / 200) % 10;

            float acc_p   = (float)tt * scale - (float)bt * scale;
            float steer_p = (float)st * scale * 2.0f - 1.0f;

            float d = acc_p - ga;
            float a = fabsf(d);
            accAS += (a < 1.0f) ? 0.5f * d * d : a - 0.5f;

            d = steer_p - gs;
            a = fabsf(d);
            accAS += (a < 1.0f) ? 0.5f * d * d : a - 0.5f;

            if (gr != PAD_IDX) {
                accR += lse - ((rev == gr) ? 1.0f : 0.0f);
                ceC  += 1.0f;
            }
        }
    }

    #pragma unroll
    for (int o = 32; o >= 1; o >>= 1) {
        accAS += __shfl_down(accAS, o);
        accR  += __shfl_down(accR,  o);
        ceC   += __shfl_down(ceC,   o);
    }
    if (lane == 0) { s_red[0][wv] = accAS; s_red[1][wv] = accR; s_red[2][wv] = ceC; }
    __syncthreads();

    if (tid == 0) {
        float rAS = 0.0f, rR = 0.0f, rC = 0.0f;
        #pragma unroll
        for (int w = 0; w < 16; ++w) {
            rAS += s_red[0][w]; rR += s_red[1][w]; rC += s_red[2][w];
        }
        out[0] = rAS / cnt;
        out[1] = rR / fmaxf(rC, 1.0f);
    }
}

extern "C" void kernel_launch(void* const* d_in, const int* in_sizes, int n_in,
                              void* d_out, int out_size, void* d_ws, size_t ws_size,
                              hipStream_t stream)
{
    const float* pred     = (const float*)d_in[0];
    const float* gt_acc   = (const float*)d_in[1];
    const float* gt_steer = (const float*)d_in[2];
    const int*   gt_rev   = (const int*)d_in[3];
    float*       out      = (float*)d_out;
    int*         tok      = (int*)d_ws;   // NROWS ints = 65280 B

    int blocks = NROWS / 16;              // 1020 blocks, 16 waves/block, 1 row/wave
    hipLaunchKernelGGL(cvl_argmax_kernel, dim3(blocks), dim3(1024), 0, stream, pred, tok);
    hipLaunchKernelGGL(cvl_loss_kernel, dim3(1), dim3(1024), 0, stream,
                       tok, gt_acc, gt_steer, gt_rev, out);
}